// Round 14
// baseline (297.784 us; speedup 1.0000x reference)
//
#include <hip/hip_runtime.h>

#define T_STEPS 512
#define BATCH 64

// fp32 casts of np.exp(-1/20), np.exp(-1/5)
__device__ constexpr float ALPHA_ = 0.95122942450071400910f;
__device__ constexpr float BETA_  = 0.81873075307798185867f;

typedef __attribute__((ext_vector_type(8))) short bf16x8;
typedef __attribute__((ext_vector_type(4))) float f32x4;

__device__ inline unsigned short f2bf_rne(float f) {
  union { float f; unsigned int u; } v{f};
  const unsigned int u = v.u;
  return (unsigned short)((u + 0x7FFFu + ((u >> 16) & 1u)) >> 16);
}
__device__ inline float bf2f(unsigned short h) {
  union { unsigned int u; float f; } v{(unsigned int)h << 16};
  return v.f;
}

__device__ inline void gload16(const void* g, void* l) {
  __builtin_amdgcn_global_load_lds(
      (const __attribute__((address_space(1))) unsigned int*)g,
      (__attribute__((address_space(3))) unsigned int*)l, 16, 0, 0);
}

// pack trunc-bf16(first) | trunc-bf16(second)<<16  (exact for spike 0/1)
__device__ inline unsigned int pkbf(float first, float second) {
#if __has_builtin(__builtin_amdgcn_perm)
  return __builtin_amdgcn_perm(__float_as_uint(second), __float_as_uint(first),
                               0x07060302u);
#else
  return (__float_as_uint(first) >> 16) | (__float_as_uint(second) & 0xFFFF0000u);
#endif
}

// 8 fp32 (lo = k0..3, hi = k4..7) -> MFMA bf16x8 fragment word order
__device__ inline bf16x8 cvt_frag(const f32x4 lo, const f32x4 hi) {
  union { unsigned int w[4]; bf16x8 v; } u;
  u.w[0] = pkbf(lo.x, lo.y);
  u.w[1] = pkbf(lo.z, lo.w);
  u.w[2] = pkbf(hi.x, hi.y);
  u.w[3] = pkbf(hi.z, hi.w);
  return u.v;
}

#define SB __builtin_amdgcn_sched_barrier(0)
#define KEEP(x) asm volatile("" ::"v"(x))

// ---------------------------------------------------------------------------
// Shared GEMM body (R8 deep-pipelined scheme) with ablation/candidate knobs:
//   VAR=0 full | VAR=1 staging-only (MFMA->keep-alives) | VAR=2 compute-only
//   (no loop VMEM) | VAR=3 A+MFMA no B-loads (vmcnt(AIP)) | VAR=4 B+MFMA no
//   A-staging (vmcnt no-op).
//   COAL: A_F32 staging re-mapped to CONTIGUOUS 8-rows x 128B per wave-instr
//   (unit u: row=u>>3, chunk=u&7) with chunk-XOR swizzle ((row&7)<<4) applied
//   to BOTH the global source and the ds_read address (2-way banks only).
// ---------------------------------------------------------------------------
template <int WM, int WC, int TM, bool A_F32, bool LNFOLD, int VAR, bool COAL>
__device__ __forceinline__ void gemm_body(
    const void* __restrict__ Av, const char* __restrict__ Bhi,
    const char* __restrict__ Blo, const float* __restrict__ uvec,
    const float* __restrict__ cvec, float* __restrict__ C, int N, int K) {
  constexpr int BM = WM * TM;
  constexpr int FM = TM / 16;                      // m-frags per wave
  constexpr int ABY = A_F32 ? BM * 128 : BM * 64;  // A bytes per K-step
  constexpr int AIP = ABY / 4096;                  // A gloads per thread
  constexpr int ASTEP = A_F32 ? 128 : 64;          // A source bytes per kb
  constexpr int W2N = AIP + 16;                    // completes A(next)
  constexpr int WV = (VAR == 3) ? AIP : ((VAR == 4) ? 16 : W2N);
  __shared__ char smem[3 * ABY];

  const int tid = threadIdx.x;
  const int lane = tid & 63;
  const int wave = tid >> 6;
  const int wm = wave / WC, wc = wave % WC;
  const int l15 = lane & 15, l4 = lane >> 4;
  const int row0 = blockIdx.y * BM;
  const int col0 = blockIdx.x * (WC * 64);
  const int KB = K / 32;

  const char* Ab = (const char*)Av;

  const char* a_src[AIP];
#pragma unroll
  for (int i = 0; i < AIP; ++i) {
    const int unit = i * 256 + tid;
    if constexpr (A_F32 && COAL) {
      const int r = unit >> 3, c = unit & 7;   // 8 rows x 128B, chunk-swizzled
      a_src[i] = Ab + ((size_t)(row0 + r) * K) * 4 + ((c * 16) ^ ((r & 7) << 4));
    } else if constexpr (A_F32) {
      const int fr = unit >> 7, h = (unit >> 6) & 1, ln = unit & 63;
      a_src[i] = Ab + ((size_t)(row0 + fr * 16 + (ln & 15)) * K + ((ln >> 4) * 8)) * 4 + h * 16;
    } else {
      const int r = ((unit >> 6) << 4) | (unit & 15);
      const int j = (unit >> 4) & 3;
      a_src[i] = Ab + ((size_t)(row0 + r) * K + j * 8) * 2;
    }
  }
  const char* bh_base = Bhi + (size_t)(blockIdx.x * WC + wc) * KB * 4096 + (size_t)lane * 16;
  const char* bl_base = Blo + (size_t)(blockIdx.x * WC + wc) * KB * 4096 + (size_t)lane * 16;

  int aoff = 0, boff = 0;
  const int amax = (KB - 1) * ASTEP;
  const int bmax = (KB - 1) * 4096;

  f32x4 acc[FM][4] = {};
  f32x4 acc1[FM] = {};
  const bf16x8 ONES = {0x3F80, 0x3F80, 0x3F80, 0x3F80,
                       0x3F80, 0x3F80, 0x3F80, 0x3F80};
  bf16x8 bh0[4], bl0[4], bh1[4], bl1[4];

#define STAGE_A(buf)                                                   \
  do {                                                                 \
    _Pragma("unroll") for (int i = 0; i < AIP; ++i)                    \
        gload16(a_src[i] + aoff, (buf) + (i * 256 + tid) * 16);        \
  } while (0)

#define LOAD_B(bh, bl, off_)                                           \
  do {                                                                 \
    const char* ph = bh_base + (off_);                                 \
    const char* pl = bl_base + (off_);                                 \
    bh[0] = *(const bf16x8*)(ph);                                      \
    bh[1] = *(const bf16x8*)(ph + 1024);                               \
    bh[2] = *(const bf16x8*)(ph + 2048);                               \
    bh[3] = *(const bf16x8*)(ph + 3072);                               \
    bl[0] = *(const bf16x8*)(pl);                                      \
    bl[1] = *(const bf16x8*)(pl + 1024);                               \
    bl[2] = *(const bf16x8*)(pl + 2048);                               \
    bl[3] = *(const bf16x8*)(pl + 3072);                               \
  } while (0)

  char* bufR = smem;
  char* bufM = smem + ABY;
  char* bufS = smem + 2 * ABY;

  // ---- prologue (identical for all variants) ----
  SB;
  STAGE_A(bufR);                      // A(0)
  SB;
  LOAD_B(bh0, bl0, 0);                // B(0)
  SB;
  aoff = ASTEP;
  STAGE_A(bufM);                      // A(1)
  SB;
  LOAD_B(bh1, bl1, 4096);             // B(1)
  SB;
  aoff = (2 * ASTEP < amax) ? 2 * ASTEP : amax;
  boff = (2 * 4096 < bmax) ? 2 * 4096 : bmax;
  asm volatile("s_waitcnt vmcnt(%0)" ::"i"(W2N) : "memory");  // A(0) landed
  __builtin_amdgcn_s_barrier();
  SB;

#define KSTEP(BH, BL)                                                        \
  do {                                                                       \
    if constexpr (VAR != 2 && VAR != 4) {                                    \
      STAGE_A(bufS); /* A(kb+2) */                                           \
      aoff = (aoff < amax) ? aoff + ASTEP : aoff;                            \
    }                                                                        \
    SB;                                                                      \
    bf16x8 af[FM];                                                           \
    _Pragma("unroll") for (int m = 0; m < FM; ++m) {                         \
      if constexpr (A_F32 && COAL) {                                         \
        const int rr = wm * TM + m * 16 + l15;                               \
        const int sw = (rr & 7) << 4;                                        \
        const f32x4 lo = *(const f32x4*)(bufR + rr * 128 + ((l4 * 32) ^ sw)); \
        const f32x4 hi = *(const f32x4*)(bufR + rr * 128 + ((l4 * 32 + 16) ^ sw)); \
        af[m] = cvt_frag(lo, hi);                                            \
      } else if constexpr (A_F32) {                                          \
        const int fr = wm * FM + m;                                          \
        const f32x4 lo = *(const f32x4*)(bufR + ((fr * 2 + 0) * 64 + lane) * 16); \
        const f32x4 hi = *(const f32x4*)(bufR + ((fr * 2 + 1) * 64 + lane) * 16); \
        af[m] = cvt_frag(lo, hi);                                            \
      } else {                                                               \
        const int fr = wm * FM + m;                                          \
        af[m] = *(const bf16x8*)(bufR + (fr * 64 + lane) * 16);              \
      }                                                                      \
    }                                                                        \
    SB;                                                                      \
    if constexpr (VAR == 1) {                                                \
      _Pragma("unroll") for (int m = 0; m < FM; ++m) KEEP(af[m]);            \
      _Pragma("unroll") for (int n = 0; n < 4; ++n) { KEEP(BH[n]); KEEP(BL[n]); } \
    } else {                                                                 \
      _Pragma("unroll") for (int m = 0; m < FM; ++m) {                       \
        _Pragma("unroll") for (int n = 0; n < 4; ++n) {                      \
          acc[m][n] = __builtin_amdgcn_mfma_f32_16x16x32_bf16(af[m], BH[n],  \
                                                              acc[m][n], 0, 0, 0); \
          acc[m][n] = __builtin_amdgcn_mfma_f32_16x16x32_bf16(af[m], BL[n],  \
                                                              acc[m][n], 0, 0, 0); \
        }                                                                    \
        if constexpr (LNFOLD)                                                \
          acc1[m] = __builtin_amdgcn_mfma_f32_16x16x32_bf16(af[m], ONES,     \
                                                            acc1[m], 0, 0, 0); \
      }                                                                      \
    }                                                                        \
    SB;                                                                      \
    if constexpr (VAR == 0 || VAR == 1 || VAR == 4) {                        \
      LOAD_B(BH, BL, boff); /* B(kb+2) */                                    \
      boff = (boff < bmax) ? boff + 4096 : boff;                             \
    }                                                                        \
    SB;                                                                      \
    if constexpr (VAR != 2)                                                  \
      asm volatile("s_waitcnt vmcnt(%0)" ::"i"(WV) : "memory");              \
    __builtin_amdgcn_s_barrier();                                            \
    SB;                                                                      \
    { char* t = bufR; bufR = bufM; bufM = bufS; bufS = t; }                  \
  } while (0)

  const int ITER = KB / 2;
  for (int it = 0; it < ITER; ++it) {
    KSTEP(bh0, bl0);
    KSTEP(bh1, bl1);
  }
  asm volatile("s_waitcnt vmcnt(0) lgkmcnt(0)" ::: "memory");

#undef KSTEP
#undef LOAD_B
#undef STAGE_A

  const int row0w = row0 + wm * TM;
  const int col0w = col0 + wc * 64;
#pragma unroll
  for (int m = 0; m < FM; ++m) {
    const int rbase = row0w + m * 16 + l4 * 4;
    float iv[4], mv[4];
    if constexpr (LNFOLD) {
#pragma unroll
      for (int r = 0; r < 4; ++r) {
        const float mean = acc1[m][r] / (float)K;
        const float inv = 1.0f / sqrtf(mean * (1.f - mean) + 1e-6f);
        iv[r] = inv;
        mv[r] = mean * inv;
      }
    }
#pragma unroll
    for (int n = 0; n < 4; ++n) {
      const int c = col0w + n * 16 + l15;
      const float cc = cvec[c];
      float uu = 0.f;
      if constexpr (LNFOLD) uu = uvec[c];
#pragma unroll
      for (int r = 0; r < 4; ++r) {
        float v;
        if constexpr (LNFOLD) v = iv[r] * acc[m][n][r] - mv[r] * uu + cc;
        else v = acc[m][n][r] + cc;
        C[(size_t)(rbase + r) * N + c] = v;
      }
    }
  }
}

// Real (production) kernels — unchanged R8 behavior.
template <int WM, int WC, int TM, bool A_F32, bool LNFOLD>
__global__ __launch_bounds__(256) void gemm_deep2(
    const void* __restrict__ Av, const char* __restrict__ Bhi,
    const char* __restrict__ Blo, const float* __restrict__ uvec,
    const float* __restrict__ cvec, float* __restrict__ C, int N, int K) {
  gemm_body<WM, WC, TM, A_F32, LNFOLD, 0, false>(Av, Bhi, Blo, uvec, cvec, C, N, K);
}

// Named diagnostics (L0 config <1,4,64,true,false>), outputs dead.
__global__ __launch_bounds__(256) void abl_stage(
    const void* Av, const char* Bhi, const char* Blo, const float* cvec, float* C, int N, int K) {
  gemm_body<1, 4, 64, true, false, 1, false>(Av, Bhi, Blo, nullptr, cvec, C, N, K);
}
__global__ __launch_bounds__(256) void abl_compute(
    const void* Av, const char* Bhi, const char* Blo, const float* cvec, float* C, int N, int K) {
  gemm_body<1, 4, 64, true, false, 2, false>(Av, Bhi, Blo, nullptr, cvec, C, N, K);
}
__global__ __launch_bounds__(256) void abl_noB(
    const void* Av, const char* Bhi, const char* Blo, const float* cvec, float* C, int N, int K) {
  gemm_body<1, 4, 64, true, false, 3, false>(Av, Bhi, Blo, nullptr, cvec, C, N, K);
}
__global__ __launch_bounds__(256) void abl_noA(
    const void* Av, const char* Bhi, const char* Blo, const float* cvec, float* C, int N, int K) {
  gemm_body<1, 4, 64, true, false, 4, false>(Av, Bhi, Blo, nullptr, cvec, C, N, K);
}
__global__ __launch_bounds__(256) void abl_coalA(
    const void* Av, const char* Bhi, const char* Blo, const float* cvec, float* C, int N, int K) {
  gemm_body<1, 4, 64, true, false, 0, true>(Av, Bhi, Blo, nullptr, cvec, C, N, K);
}

// ---------------------------------------------------------------------------
// Prep: W[K,N] f32 (optionally scaled by s[k]) -> split hi/lo bf16 in the
// fragment-linear (64-col-block) global layout consumed by the GEMMs.
// ---------------------------------------------------------------------------
__global__ void prep_split(const float* __restrict__ W, const float* __restrict__ s,
                           char* __restrict__ hi, char* __restrict__ lo,
                           int K, int N) {
  const int g = blockIdx.x * 256 + threadIdx.x;
  const int total = (K * N) / 8;
  if (g >= total) return;
  constexpr int UB = 256;
  const int KB = K / 32;
  const int unit = g % UB;
  const int kb = (g / UB) % KB;
  const int cb = g / (UB * KB);
  const int n = cb * 64 + ((unit >> 6) << 4) + (unit & 15);
  const int kbase = kb * 32 + ((unit >> 4) & 3) * 8;
  short h8[8], l8[8];
#pragma unroll
  for (int jj = 0; jj < 8; ++jj) {
    const int k = kbase + jj;
    float w = W[(size_t)k * N + n];
    if (s) w *= s[k];
    const unsigned short hb = f2bf_rne(w);
    const unsigned short lb = f2bf_rne(w - bf2f(hb));
    h8[jj] = (short)hb;
    l8[jj] = (short)lb;
  }
  *(bf16x8*)(hi + (size_t)g * 16) = *(const bf16x8*)h8;
  *(bf16x8*)(lo + (size_t)g * 16) = *(const bf16x8*)l8;
}

// u[n] = sum_k s[k]*W[k,n];  c[n] = sum_k b[k]*W[k,n] + bias2[n]. Block per n.
__global__ __launch_bounds__(256) void prep_consts(
    const float* __restrict__ W, const float* __restrict__ s,
    const float* __restrict__ b, const float* __restrict__ bias2,
    float* __restrict__ u, float* __restrict__ c, int K, int N) {
  const int n = blockIdx.x;
  const int t = threadIdx.x;
  float us = 0.f, cs = 0.f;
  for (int k = t; k < K; k += 256) {
    const float w = W[(size_t)k * N + n];
    us += s[k] * w;
    cs += b[k] * w;
  }
  __shared__ float su[256], sc[256];
  su[t] = us;
  sc[t] = cs;
  __syncthreads();
  for (int o = 128; o > 0; o >>= 1) {
    if (t < o) { su[t] += su[t + o]; sc[t] += sc[t + o]; }
    __syncthreads();
  }
  if (t == 0) { u[n] = su[0]; c[n] = sc[0] + bias2[n]; }
}

// ---------------------------------------------------------------------------
// LIF scan over T, one thread per (b,h); reads fp32 currents, writes bf16
// spikes (exact) and/or per-(b,h) spike counts. 32x unrolled loads.
// ---------------------------------------------------------------------------
template <int H, bool SPIKE_OUT, bool ACCUM>
__global__ void lif_scan(const float* __restrict__ xt,
                         unsigned short* __restrict__ sp,
                         float* __restrict__ tsum) {
  const int n = blockIdx.x * 64 + threadIdx.x;
  const int b = n / H, h = n % H;
  const float* p = xt + (size_t)b * T_STEPS * H + h;
  unsigned short* q = nullptr;
  if constexpr (SPIKE_OUT) q = sp + (size_t)b * T_STEPS * H + h;

  float v = 0.f, cur = 0.f, ts = 0.f;
  for (int t = 0; t < T_STEPS; t += 32) {
    float x[32];
#pragma unroll
    for (int u = 0; u < 32; ++u) x[u] = p[(size_t)u * H];
#pragma unroll
    for (int u = 0; u < 32; ++u) {
      cur = BETA_ * cur + x[u];
      v = ALPHA_ * v + cur;
      const bool sb = (v >= 1.f);
      if constexpr (SPIKE_OUT) q[(size_t)u * H] = sb ? 0x3F80 : 0;
      if constexpr (ACCUM) ts += sb ? 1.f : 0.f;
      v = sb ? 0.f : v;
    }
    p += (size_t)32 * H;
    if constexpr (SPIKE_OUT) q += (size_t)32 * H;
  }
  if constexpr (ACCUM) tsum[n] = ts;
}

__global__ void finalize(const float* __restrict__ tsum,
                         const float* __restrict__ Wc,
                         const float* __restrict__ bc,
                         float* __restrict__ out) {
  const int b = threadIdx.x;  // 64 threads, one wave
  float s = 0.f;
#pragma unroll 8
  for (int h = 0; h < 64; ++h) s += tsum[b * 64 + h];
  const float pooled = s * (1.0f / (512.f * 64.f));
  out[2 + b] = pooled;

  float tot = pooled;
  float l0 = pooled * Wc[b * 2 + 0];
  float l1 = pooled * Wc[b * 2 + 1];
#pragma unroll
  for (int off = 32; off > 0; off >>= 1) {
    tot += __shfl_xor(tot, off);
    l0 += __shfl_xor(l0, off);
    l1 += __shfl_xor(l1, off);
  }
  if (b == 0) {
    out[0] = l0 + bc[0];
    out[1] = l1 + bc[1];
    out[66] = tot * (1.0f / 64.f);
  }
}

extern "C" void kernel_launch(void* const* d_in, const int* in_sizes, int n_in,
                              void* d_out, int out_size, void* d_ws, size_t ws_size,
                              hipStream_t stream) {
  const float* X    = (const float*)d_in[0];   // [64,512,64,16] -> [32768,1024]
  const float* W0   = (const float*)d_in[1];   // [1024,256]
  const float* b0   = (const float*)d_in[2];
  const float* W1   = (const float*)d_in[3];   // [256,128]
  const float* b1   = (const float*)d_in[4];
  const float* W2   = (const float*)d_in[5];   // [128,64]
  const float* b2   = (const float*)d_in[6];
  const float* ln1s = (const float*)d_in[7];
  const float* ln1b = (const float*)d_in[8];
  const float* ln2s = (const float*)d_in[9];
  const float* ln2b = (const float*)d_in[10];
  const float* Wc   = (const float*)d_in[11];  // [64,2]
  const float* bc   = (const float*)d_in[12];
  float* out = (float*)d_out;

  char* w = (char*)d_ws;
  float* buf0 = (float*)w;                       // [32768,256] f32 = 33554432 B
  float* buf1 = (float*)w;                       // alias: buf0 dead after scan0
  float* buf2 = (float*)(w + 16777216);          // [32768,64] f32, after buf1
  size_t off = 33554432;
  unsigned short* sp0 = (unsigned short*)(w + off); off += 16777216;  // [32768,256] bf16
  unsigned short* sp1 = (unsigned short*)(w + off); off += 8388608;   // [32768,128] bf16
  char* hi0 = w + off; off += 524288;
  char* lo0 = w + off; off += 524288;
  char* hi1 = w + off; off += 65536;
  char* lo1 = w + off; off += 65536;
  char* hi2 = w + off; off += 16384;
  char* lo2 = w + off; off += 16384;
  float* u1 = (float*)(w + off); off += 512;
  float* c1 = (float*)(w + off); off += 512;
  float* u2 = (float*)(w + off); off += 256;
  float* c2 = (float*)(w + off); off += 256;
  float* tsum = (float*)(w + off); off += 16384;

  const int M = 32768;

  // --- weight prep (frag-linear 64-col-block split hi/lo + LN-fold consts) ---
  prep_split<<<128, 256, 0, stream>>>(W0, nullptr, hi0, lo0, 1024, 256);
  prep_split<<<16, 256, 0, stream>>>(W1, ln1s, hi1, lo1, 256, 128);
  prep_split<<<4, 256, 0, stream>>>(W2, ln2s, hi2, lo2, 128, 64);
  prep_consts<<<128, 256, 0, stream>>>(W1, ln1s, ln1b, b1, u1, c1, 256, 128);
  prep_consts<<<64, 256, 0, stream>>>(W2, ln2s, ln2b, b2, u2, c2, 128, 64);

  // --- layer 0 (REAL): R8 config, BM=64, BN=256, grid (1,512). ---
  gemm_deep2<1, 4, 64, true, false><<<dim3(1, M / 64), 256, 0, stream>>>(
      X, hi0, lo0, nullptr, b0, buf0, 256, 1024);
  lif_scan<256, true, false><<<(BATCH * 256) / 64, 64, 0, stream>>>(buf0, sp0, nullptr);

  // --- layer 1: LN folded (rowsum via ones-MFMA). R8 config. ---
  gemm_deep2<2, 2, 32, false, true><<<dim3(1, M / 64), 256, 0, stream>>>(
      sp0, hi1, lo1, u1, c1, buf1, 128, 256);
  lif_scan<128, true, false><<<(BATCH * 128) / 64, 64, 0, stream>>>(buf1, sp1, nullptr);

  // --- layer 2: R8 config. ---
  gemm_deep2<4, 1, 32, false, true><<<dim3(1, M / 128), 256, 0, stream>>>(
      sp1, hi2, lo2, u2, c2, buf2, 64, 128);
  lif_scan<64, false, true><<<(BATCH * 64) / 64, 64, 0, stream>>>(buf2, nullptr, tsum);

  finalize<<<1, 64, 0, stream>>>(tsum, Wc, bc, out);

  // ======== NAMED DIAGNOSTICS of the L0 GEMM (write to dead buf0) ==========
  abl_stage<<<dim3(1, M / 64), 256, 0, stream>>>(X, hi0, lo0, b0, buf0, 256, 1024);
  abl_compute<<<dim3(1, M / 64), 256, 0, stream>>>(X, hi0, lo0, b0, buf0, 256, 1024);
  abl_noB<<<dim3(1, M / 64), 256, 0, stream>>>(X, hi0, lo0, b0, buf0, 256, 1024);
  abl_noA<<<dim3(1, M / 64), 256, 0, stream>>>(X, hi0, lo0, b0, buf0, 256, 1024);
  abl_coalA<<<dim3(1, M / 64), 256, 0, stream>>>(X, hi0, lo0, b0, buf0, 256, 1024);
}

// Round 15
// 126.750 us; speedup vs baseline: 2.3494x; 2.3494x over previous
//
#include <hip/hip_runtime.h>

#define T_STEPS 512
#define BATCH 64

// fp32 casts of np.exp(-1/20), np.exp(-1/5)
__device__ constexpr float ALPHA_ = 0.95122942450071400910f;
__device__ constexpr float BETA_  = 0.81873075307798185867f;

typedef __attribute__((ext_vector_type(8))) short bf16x8;
typedef __attribute__((ext_vector_type(4))) float f32x4;

__device__ inline unsigned short f2bf_rne(float f) {
  union { float f; unsigned int u; } v{f};
  const unsigned int u = v.u;
  return (unsigned short)((u + 0x7FFFu + ((u >> 16) & 1u)) >> 16);
}
__device__ inline float bf2f(unsigned short h) {
  union { unsigned int u; float f; } v{(unsigned int)h << 16};
  return v.f;
}

__device__ inline void gload16(const void* g, void* l) {
  __builtin_amdgcn_global_load_lds(
      (const __attribute__((address_space(1))) unsigned int*)g,
      (__attribute__((address_space(3))) unsigned int*)l, 16, 0, 0);
}

// pack trunc-bf16(first) | trunc-bf16(second)<<16  (exact for spike 0/1)
__device__ inline unsigned int pkbf(float first, float second) {
#if __has_builtin(__builtin_amdgcn_perm)
  return __builtin_amdgcn_perm(__float_as_uint(second), __float_as_uint(first),
                               0x07060302u);
#else
  return (__float_as_uint(first) >> 16) | (__float_as_uint(second) & 0xFFFF0000u);
#endif
}

// 8 fp32 (lo = k0..3, hi = k4..7) -> MFMA bf16x8 fragment word order
__device__ inline bf16x8 cvt_frag(const f32x4 lo, const f32x4 hi) {
  union { unsigned int w[4]; bf16x8 v; } u;
  u.w[0] = pkbf(lo.x, lo.y);
  u.w[1] = pkbf(lo.z, lo.w);
  u.w[2] = pkbf(hi.x, hi.y);
  u.w[3] = pkbf(hi.z, hi.w);
  return u.v;
}

#define SB __builtin_amdgcn_sched_barrier(0)

// ---------------------------------------------------------------------------
// R8 deep-pipelined GEMM with COALESCED A staging (R14 diagnostic winner):
//   COAL (A_F32 only): A staged as CONTIGUOUS 8-rows x 128B per wave-instr
//   (unit u: row=u>>3, chunk=u&7), chunk-XOR swizzle ((row&7)<<4) applied to
//   BOTH the global source and the ds_read address — full 128B line
//   utilization, half the transactions of the old 16-rows x 64B gather.
//   R14 ablation: full-GEMM-with-COAL ran faster than the production kernel.
//   A: global_load_lds, TRIPLE-buffered, depth-2; counted s_waitcnt
//   vmcnt(AIP+16) before the raw s_barrier completes exactly A(next).
//   B: frag-linear hi/lo bf16 (L2-resident), plain C++ loads into ping-pong
//   register sets; compiler inserts exact waits for them.
// LNFOLD: rowsum via ones-MFMA; epilogue inv[r]*acc - mi[r]*u[c] + c[c].
// ---------------------------------------------------------------------------
template <int WM, int WC, int TM, bool A_F32, bool LNFOLD, bool COAL>
__global__ __launch_bounds__(256) void gemm_deep2(
    const void* __restrict__ Av, const char* __restrict__ Bhi,
    const char* __restrict__ Blo, const float* __restrict__ uvec,
    const float* __restrict__ cvec, float* __restrict__ C, int N, int K) {
  constexpr int BM = WM * TM;
  constexpr int FM = TM / 16;                      // m-frags per wave
  constexpr int ABY = A_F32 ? BM * 128 : BM * 64;  // A bytes per K-step
  constexpr int AIP = ABY / 4096;                  // A gloads per thread
  constexpr int ASTEP = A_F32 ? 128 : 64;          // A source bytes per kb
  constexpr int W2N = AIP + 16;                    // completes A(next)
  __shared__ char smem[3 * ABY];

  const int tid = threadIdx.x;
  const int lane = tid & 63;
  const int wave = tid >> 6;
  const int wm = wave / WC, wc = wave % WC;
  const int l15 = lane & 15, l4 = lane >> 4;
  const int row0 = blockIdx.y * BM;
  const int col0 = blockIdx.x * (WC * 64);
  const int KB = K / 32;

  const char* Ab = (const char*)Av;

  const char* a_src[AIP];
#pragma unroll
  for (int i = 0; i < AIP; ++i) {
    const int unit = i * 256 + tid;
    if constexpr (A_F32 && COAL) {
      const int r = unit >> 3, c = unit & 7;   // 8 rows x 128B, chunk-swizzled
      a_src[i] = Ab + ((size_t)(row0 + r) * K) * 4 + ((c * 16) ^ ((r & 7) << 4));
    } else if constexpr (A_F32) {
      const int fr = unit >> 7, h = (unit >> 6) & 1, ln = unit & 63;
      a_src[i] = Ab + ((size_t)(row0 + fr * 16 + (ln & 15)) * K + ((ln >> 4) * 8)) * 4 + h * 16;
    } else {
      const int r = ((unit >> 6) << 4) | (unit & 15);
      const int j = (unit >> 4) & 3;
      a_src[i] = Ab + ((size_t)(row0 + r) * K + j * 8) * 2;
    }
  }
  const char* bh_base = Bhi + (size_t)(blockIdx.x * WC + wc) * KB * 4096 + (size_t)lane * 16;
  const char* bl_base = Blo + (size_t)(blockIdx.x * WC + wc) * KB * 4096 + (size_t)lane * 16;

  int aoff = 0, boff = 0;
  const int amax = (KB - 1) * ASTEP;
  const int bmax = (KB - 1) * 4096;

  f32x4 acc[FM][4] = {};
  f32x4 acc1[FM] = {};
  const bf16x8 ONES = {0x3F80, 0x3F80, 0x3F80, 0x3F80,
                       0x3F80, 0x3F80, 0x3F80, 0x3F80};
  bf16x8 bh0[4], bl0[4], bh1[4], bl1[4];

#define STAGE_A(buf)                                                   \
  do {                                                                 \
    _Pragma("unroll") for (int i = 0; i < AIP; ++i)                    \
        gload16(a_src[i] + aoff, (buf) + (i * 256 + tid) * 16);        \
  } while (0)

#define LOAD_B(bh, bl, off_)                                           \
  do {                                                                 \
    const char* ph = bh_base + (off_);                                 \
    const char* pl = bl_base + (off_);                                 \
    bh[0] = *(const bf16x8*)(ph);                                      \
    bh[1] = *(const bf16x8*)(ph + 1024);                               \
    bh[2] = *(const bf16x8*)(ph + 2048);                               \
    bh[3] = *(const bf16x8*)(ph + 3072);                               \
    bl[0] = *(const bf16x8*)(pl);                                      \
    bl[1] = *(const bf16x8*)(pl + 1024);                               \
    bl[2] = *(const bf16x8*)(pl + 2048);                               \
    bl[3] = *(const bf16x8*)(pl + 3072);                               \
  } while (0)

  char* bufR = smem;
  char* bufM = smem + ABY;
  char* bufS = smem + 2 * ABY;

  // ---- prologue ----
  SB;
  STAGE_A(bufR);                      // A(0)
  SB;
  LOAD_B(bh0, bl0, 0);                // B(0)
  SB;
  aoff = ASTEP;
  STAGE_A(bufM);                      // A(1)
  SB;
  LOAD_B(bh1, bl1, 4096);             // B(1)
  SB;
  aoff = (2 * ASTEP < amax) ? 2 * ASTEP : amax;
  boff = (2 * 4096 < bmax) ? 2 * 4096 : bmax;
  asm volatile("s_waitcnt vmcnt(%0)" ::"i"(W2N) : "memory");  // A(0) landed
  __builtin_amdgcn_s_barrier();
  SB;

#define KSTEP(BH, BL)                                                        \
  do {                                                                       \
    STAGE_A(bufS); /* A(kb+2) */                                             \
    aoff = (aoff < amax) ? aoff + ASTEP : aoff;                              \
    SB;                                                                      \
    bf16x8 af[FM];                                                           \
    _Pragma("unroll") for (int m = 0; m < FM; ++m) {                         \
      if constexpr (A_F32 && COAL) {                                         \
        const int rr = wm * TM + m * 16 + l15;                               \
        const int sw = (rr & 7) << 4;                                        \
        const f32x4 lo = *(const f32x4*)(bufR + rr * 128 + ((l4 * 32) ^ sw)); \
        const f32x4 hi = *(const f32x4*)(bufR + rr * 128 + ((l4 * 32 + 16) ^ sw)); \
        af[m] = cvt_frag(lo, hi);                                            \
      } else if constexpr (A_F32) {                                          \
        const int fr = wm * FM + m;                                          \
        const f32x4 lo = *(const f32x4*)(bufR + ((fr * 2 + 0) * 64 + lane) * 16); \
        const f32x4 hi = *(const f32x4*)(bufR + ((fr * 2 + 1) * 64 + lane) * 16); \
        af[m] = cvt_frag(lo, hi);                                            \
      } else {                                                               \
        const int fr = wm * FM + m;                                          \
        af[m] = *(const bf16x8*)(bufR + (fr * 64 + lane) * 16);              \
      }                                                                      \
    }                                                                        \
    SB;                                                                      \
    _Pragma("unroll") for (int m = 0; m < FM; ++m) {                         \
      _Pragma("unroll") for (int n = 0; n < 4; ++n) {                        \
        acc[m][n] = __builtin_amdgcn_mfma_f32_16x16x32_bf16(af[m], BH[n],    \
                                                            acc[m][n], 0, 0, 0); \
        acc[m][n] = __builtin_amdgcn_mfma_f32_16x16x32_bf16(af[m], BL[n],    \
                                                            acc[m][n], 0, 0, 0); \
      }                                                                      \
      if constexpr (LNFOLD)                                                  \
        acc1[m] = __builtin_amdgcn_mfma_f32_16x16x32_bf16(af[m], ONES,       \
                                                          acc1[m], 0, 0, 0); \
    }                                                                        \
    SB;                                                                      \
    LOAD_B(BH, BL, boff); /* B(kb+2) */                                      \
    boff = (boff < bmax) ? boff + 4096 : boff;                               \
    SB;                                                                      \
    asm volatile("s_waitcnt vmcnt(%0)" ::"i"(W2N) : "memory");               \
    __builtin_amdgcn_s_barrier();                                            \
    SB;                                                                      \
    { char* t = bufR; bufR = bufM; bufM = bufS; bufS = t; }                  \
  } while (0)

  const int ITER = KB / 2;
  for (int it = 0; it < ITER; ++it) {
    KSTEP(bh0, bl0);
    KSTEP(bh1, bl1);
  }
  asm volatile("s_waitcnt vmcnt(0) lgkmcnt(0)" ::: "memory");

#undef KSTEP
#undef LOAD_B
#undef STAGE_A

  const int row0w = row0 + wm * TM;
  const int col0w = col0 + wc * 64;
#pragma unroll
  for (int m = 0; m < FM; ++m) {
    const int rbase = row0w + m * 16 + l4 * 4;
    float iv[4], mv[4];
    if constexpr (LNFOLD) {
#pragma unroll
      for (int r = 0; r < 4; ++r) {
        const float mean = acc1[m][r] / (float)K;
        const float inv = 1.0f / sqrtf(mean * (1.f - mean) + 1e-6f);
        iv[r] = inv;
        mv[r] = mean * inv;
      }
    }
#pragma unroll
    for (int n = 0; n < 4; ++n) {
      const int c = col0w + n * 16 + l15;
      const float cc = cvec[c];
      float uu = 0.f;
      if constexpr (LNFOLD) uu = uvec[c];
#pragma unroll
      for (int r = 0; r < 4; ++r) {
        float v;
        if constexpr (LNFOLD) v = iv[r] * acc[m][n][r] - mv[r] * uu + cc;
        else v = acc[m][n][r] + cc;
        C[(size_t)(rbase + r) * N + c] = v;
      }
    }
  }
}

// ---------------------------------------------------------------------------
// Prep: W[K,N] f32 (optionally scaled by s[k]) -> split hi/lo bf16 in the
// fragment-linear (64-col-block) global layout consumed by the GEMMs.
// ---------------------------------------------------------------------------
__global__ void prep_split(const float* __restrict__ W, const float* __restrict__ s,
                           char* __restrict__ hi, char* __restrict__ lo,
                           int K, int N) {
  const int g = blockIdx.x * 256 + threadIdx.x;
  const int total = (K * N) / 8;
  if (g >= total) return;
  constexpr int UB = 256;
  const int KB = K / 32;
  const int unit = g % UB;
  const int kb = (g / UB) % KB;
  const int cb = g / (UB * KB);
  const int n = cb * 64 + ((unit >> 6) << 4) + (unit & 15);
  const int kbase = kb * 32 + ((unit >> 4) & 3) * 8;
  short h8[8], l8[8];
#pragma unroll
  for (int jj = 0; jj < 8; ++jj) {
    const int k = kbase + jj;
    float w = W[(size_t)k * N + n];
    if (s) w *= s[k];
    const unsigned short hb = f2bf_rne(w);
    const unsigned short lb = f2bf_rne(w - bf2f(hb));
    h8[jj] = (short)hb;
    l8[jj] = (short)lb;
  }
  *(bf16x8*)(hi + (size_t)g * 16) = *(const bf16x8*)h8;
  *(bf16x8*)(lo + (size_t)g * 16) = *(const bf16x8*)l8;
}

// u[n] = sum_k s[k]*W[k,n];  c[n] = sum_k b[k]*W[k,n] + bias2[n]. Block per n.
__global__ __launch_bounds__(256) void prep_consts(
    const float* __restrict__ W, const float* __restrict__ s,
    const float* __restrict__ b, const float* __restrict__ bias2,
    float* __restrict__ u, float* __restrict__ c, int K, int N) {
  const int n = blockIdx.x;
  const int t = threadIdx.x;
  float us = 0.f, cs = 0.f;
  for (int k = t; k < K; k += 256) {
    const float w = W[(size_t)k * N + n];
    us += s[k] * w;
    cs += b[k] * w;
  }
  __shared__ float su[256], sc[256];
  su[t] = us;
  sc[t] = cs;
  __syncthreads();
  for (int o = 128; o > 0; o >>= 1) {
    if (t < o) { su[t] += su[t + o]; sc[t] += sc[t + o]; }
    __syncthreads();
  }
  if (t == 0) { u[n] = su[0]; c[n] = sc[0] + bias2[n]; }
}

// ---------------------------------------------------------------------------
// LIF scan over T, one thread per (b,h); reads fp32 currents, writes bf16
// spikes (exact) and/or per-(b,h) spike counts. 32x unrolled loads.
// ---------------------------------------------------------------------------
template <int H, bool SPIKE_OUT, bool ACCUM>
__global__ void lif_scan(const float* __restrict__ xt,
                         unsigned short* __restrict__ sp,
                         float* __restrict__ tsum) {
  const int n = blockIdx.x * 64 + threadIdx.x;
  const int b = n / H, h = n % H;
  const float* p = xt + (size_t)b * T_STEPS * H + h;
  unsigned short* q = nullptr;
  if constexpr (SPIKE_OUT) q = sp + (size_t)b * T_STEPS * H + h;

  float v = 0.f, cur = 0.f, ts = 0.f;
  for (int t = 0; t < T_STEPS; t += 32) {
    float x[32];
#pragma unroll
    for (int u = 0; u < 32; ++u) x[u] = p[(size_t)u * H];
#pragma unroll
    for (int u = 0; u < 32; ++u) {
      cur = BETA_ * cur + x[u];
      v = ALPHA_ * v + cur;
      const bool sb = (v >= 1.f);
      if constexpr (SPIKE_OUT) q[(size_t)u * H] = sb ? 0x3F80 : 0;
      if constexpr (ACCUM) ts += sb ? 1.f : 0.f;
      v = sb ? 0.f : v;
    }
    p += (size_t)32 * H;
    if constexpr (SPIKE_OUT) q += (size_t)32 * H;
  }
  if constexpr (ACCUM) tsum[n] = ts;
}

__global__ void finalize(const float* __restrict__ tsum,
                         const float* __restrict__ Wc,
                         const float* __restrict__ bc,
                         float* __restrict__ out) {
  const int b = threadIdx.x;  // 64 threads, one wave
  float s = 0.f;
#pragma unroll 8
  for (int h = 0; h < 64; ++h) s += tsum[b * 64 + h];
  const float pooled = s * (1.0f / (512.f * 64.f));
  out[2 + b] = pooled;

  float tot = pooled;
  float l0 = pooled * Wc[b * 2 + 0];
  float l1 = pooled * Wc[b * 2 + 1];
#pragma unroll
  for (int off = 32; off > 0; off >>= 1) {
    tot += __shfl_xor(tot, off);
    l0 += __shfl_xor(l0, off);
    l1 += __shfl_xor(l1, off);
  }
  if (b == 0) {
    out[0] = l0 + bc[0];
    out[1] = l1 + bc[1];
    out[66] = tot * (1.0f / 64.f);
  }
}

extern "C" void kernel_launch(void* const* d_in, const int* in_sizes, int n_in,
                              void* d_out, int out_size, void* d_ws, size_t ws_size,
                              hipStream_t stream) {
  const float* X    = (const float*)d_in[0];   // [64,512,64,16] -> [32768,1024]
  const float* W0   = (const float*)d_in[1];   // [1024,256]
  const float* b0   = (const float*)d_in[2];
  const float* W1   = (const float*)d_in[3];   // [256,128]
  const float* b1   = (const float*)d_in[4];
  const float* W2   = (const float*)d_in[5];   // [128,64]
  const float* b2   = (const float*)d_in[6];
  const float* ln1s = (const float*)d_in[7];
  const float* ln1b = (const float*)d_in[8];
  const float* ln2s = (const float*)d_in[9];
  const float* ln2b = (const float*)d_in[10];
  const float* Wc   = (const float*)d_in[11];  // [64,2]
  const float* bc   = (const float*)d_in[12];
  float* out = (float*)d_out;

  char* w = (char*)d_ws;
  float* buf0 = (float*)w;                       // [32768,256] f32 = 33554432 B
  float* buf1 = (float*)w;                       // alias: buf0 dead after scan0
  float* buf2 = (float*)(w + 16777216);          // [32768,64] f32, after buf1
  size_t off = 33554432;
  unsigned short* sp0 = (unsigned short*)(w + off); off += 16777216;  // [32768,256] bf16
  unsigned short* sp1 = (unsigned short*)(w + off); off += 8388608;   // [32768,128] bf16
  char* hi0 = w + off; off += 524288;
  char* lo0 = w + off; off += 524288;
  char* hi1 = w + off; off += 65536;
  char* lo1 = w + off; off += 65536;
  char* hi2 = w + off; off += 16384;
  char* lo2 = w + off; off += 16384;
  float* u1 = (float*)(w + off); off += 512;
  float* c1 = (float*)(w + off); off += 512;
  float* u2 = (float*)(w + off); off += 256;
  float* c2 = (float*)(w + off); off += 256;
  float* tsum = (float*)(w + off); off += 16384;

  const int M = 32768;

  // --- weight prep (frag-linear 64-col-block split hi/lo + LN-fold consts) ---
  prep_split<<<128, 256, 0, stream>>>(W0, nullptr, hi0, lo0, 1024, 256);
  prep_split<<<16, 256, 0, stream>>>(W1, ln1s, hi1, lo1, 256, 128);
  prep_split<<<4, 256, 0, stream>>>(W2, ln2s, hi2, lo2, 128, 64);
  prep_consts<<<128, 256, 0, stream>>>(W1, ln1s, ln1b, b1, u1, c1, 256, 128);
  prep_consts<<<64, 256, 0, stream>>>(W2, ln2s, ln2b, b2, u2, c2, 128, 64);

  // --- layer 0: R8 config + COALESCED A staging (R14 diagnostic winner).
  //     BM=64, BN=256, grid (1,512). ---
  gemm_deep2<1, 4, 64, true, false, true><<<dim3(1, M / 64), 256, 0, stream>>>(
      X, hi0, lo0, nullptr, b0, buf0, 256, 1024);
  lif_scan<256, true, false><<<(BATCH * 256) / 64, 64, 0, stream>>>(buf0, sp0, nullptr);

  // --- layer 1: LN folded (rowsum via ones-MFMA). R8 config. ---
  gemm_deep2<2, 2, 32, false, true, false><<<dim3(1, M / 64), 256, 0, stream>>>(
      sp0, hi1, lo1, u1, c1, buf1, 128, 256);
  lif_scan<128, true, false><<<(BATCH * 128) / 64, 64, 0, stream>>>(buf1, sp1, nullptr);

  // --- layer 2: R8 config. ---
  gemm_deep2<4, 1, 32, false, true, false><<<dim3(1, M / 128), 256, 0, stream>>>(
      sp1, hi2, lo2, u2, c2, buf2, 64, 128);
  lif_scan<64, false, true><<<(BATCH * 64) / 64, 64, 0, stream>>>(buf2, nullptr, tsum);

  finalize<<<1, 64, 0, stream>>>(tsum, Wc, bc, out);
}